// Round 1
// baseline (250.584 us; speedup 1.0000x reference)
//
#include <hip/hip_runtime.h>

#define SS 128
#define RR 128
#define CC 128
#define SCH 4          // s-slabs marched per block; redundancy (SCH+1)/SCH on U
#define EPSF 1e-14f

// Block = 256 threads = 8 rows x 32 float4-cols. Each block marches SCH
// consecutive s-slabs, keeping the previous slab's 9 channels in registers so
// the s-direction diff needs NO re-read (was +9 float4 far-miss loads/thread).
// r-diff re-reads row+1, which 7/8 of the time is this block's own just-loaded
// data (L1/L2 hit); row 7 reads the neighbor r-tile (same XCD via swizzle).
// c-diff boundary via __shfl_down as before.
__global__ __launch_bounds__(256, 4) void scol_main(const float* __restrict__ L,
                                                    const float* __restrict__ U,
                                                    float4* __restrict__ part) {
    const int SRC = SS * RR * CC;
    const int RC  = RR * CC;

    // bijective XCD swizzle: grid = 512*B blocks, divisible by 8.
    // Consecutive logical blocks (rt fastest, then sc) land on one XCD ->
    // r-tile and s-chunk boundary re-reads hit that XCD's L2.
    int bid = blockIdx.x;
    int cpx = gridDim.x >> 3;
    int swz = (bid & 7) * cpx + (bid >> 3);

    int rt = swz & 15;           // r-tile: 16 tiles of 8 rows
    int sc = (swz >> 4) & 31;    // s-chunk: 32 chunks of SCH=4
    int b  = swz >> 9;           // batch

    int tid = threadIdx.x;
    int c4       = tid & 31;
    int rowLocal = tid >> 5;     // 0..7
    int r  = (rt << 3) + rowLocal;
    int s0 = sc * SCH;
    int c  = c4 << 2;

    bool hr = (r < RR - 1), hc = (c4 < 31);
    float wr = hr ? 1.f : 0.f;
    float wc = hc ? 1.f : 0.f;
    int offr = hr ? CC : 0;      // clamped: boundary re-loads self, weight 0

    int pos = (s0 * RR + r) * CC + c;
    const float* Ub = U + (size_t)b * 9 * SRC + pos;
    const float* Lb = L + (size_t)b * 3 * SRC + pos;

    float a_dc = 0.f, a_dr = 0.f, a_ds = 0.f, a_co = 0.f;

    // preload slab s0 into prev; the ss==0 s-diff below is then exactly 0
    // (identical slabs) and the re-load is an L1 hit. Keeps the loop uniform.
    float4 prev[9];
#pragma unroll
    for (int ch = 0; ch < 9; ++ch)
        prev[ch] = *(const float4*)(Ub + ch * SRC);

#pragma unroll 1
    for (int ss = 0; ss < SCH; ++ss) {
        const float* Up = Ub + ss * RC;
        const float* Lp = Lb + ss * RC;

        float4 l0 = *(const float4*)(Lp);
        float4 l1 = *(const float4*)(Lp + SRC);
        float4 l2 = *(const float4*)(Lp + 2 * SRC);
        float L0v[4] = {l0.x, l0.y, l0.z, l0.w};
        float L1v[4] = {l1.x, l1.y, l1.z, l1.w};
        float L2v[4] = {l2.x, l2.y, l2.z, l2.w};
        int idx[4];
#pragma unroll
        for (int j = 0; j < 4; ++j) {
            int id = 0;
            float best = L0v[j];
            if (L1v[j] > best) { best = L1v[j]; id = 1; }
            if (L2v[j] > best) { best = L2v[j]; id = 2; }
            idx[j] = id;
        }

        float am[3][4];
#pragma unroll
        for (int g = 0; g < 3; ++g)
#pragma unroll
            for (int j = 0; j < 4; ++j) am[g][j] = 0.f;

        float t_dcb = 0.f, t_dr = 0.f;

#pragma unroll
        for (int ch = 0; ch < 9; ++ch) {
            float4 uu = *(const float4*)(Up + ch * SRC);
            float4 vr = *(const float4*)(Up + ch * SRC + offr);
            float4 pv = prev[ch];

            int g = ch / 3, m = ch % 3;
            float uuv[4] = {uu.x, uu.y, uu.z, uu.w};
#pragma unroll
            for (int j = 0; j < 4; ++j)
                if (idx[j] == m) am[g][j] = fabsf(uuv[j]);

            float d;
            // c-diffs (3 internal + 1 boundary via shfl; lane31/63 masked by wc)
            d = uu.y - uu.x; a_dc += d * d;
            d = uu.z - uu.y; a_dc += d * d;
            d = uu.w - uu.z; a_dc += d * d;
            float un = __shfl_down(uu.x, 1);
            d = un - uu.w; t_dcb += d * d;

            // r-diff (row+1: same-block L1/L2 hit for rows 0..6)
            d = vr.x - uu.x; t_dr += d * d;
            d = vr.y - uu.y; t_dr += d * d;
            d = vr.z - uu.z; t_dr += d * d;
            d = vr.w - uu.w; t_dr += d * d;

            // s-diff vs previous slab held in registers (ss==0 contributes 0)
            d = uu.x - pv.x; a_ds += d * d;
            d = uu.y - pv.y; a_ds += d * d;
            d = uu.z - pv.z; a_ds += d * d;
            d = uu.w - pv.w; a_ds += d * d;

            prev[ch] = uu;
        }
        a_dc += wc * t_dcb;
        a_dr += wr * t_dr;

#pragma unroll
        for (int j = 0; j < 4; ++j) {
            float e1 = am[0][j], e2 = am[1][j], e3 = am[2][j];
            float den = e1 * e1 + e2 * e2 + e3 * e3;
            den = fmaxf(den, EPSF);
            float num = 0.5f * ((e1 - e2) * (e1 - e2) + (e2 - e3) * (e2 - e3) +
                                (e3 - e1) * (e3 - e1));
            a_co += sqrtf(num / den);
        }
    }

    // chunk-boundary s-diff: slab s0+SCH (next chunk's first slab, L2/L3 hit
    // against the co-resident neighbor block) vs prev = slab s0+SCH-1.
    if (s0 + SCH < SS) {
        const float* Up = Ub + SCH * RC;
#pragma unroll
        for (int ch = 0; ch < 9; ++ch) {
            float4 uu = *(const float4*)(Up + ch * SRC);
            float4 pv = prev[ch];
            float d;
            d = uu.x - pv.x; a_ds += d * d;
            d = uu.y - pv.y; a_ds += d * d;
            d = uu.z - pv.z; a_ds += d * d;
            d = uu.w - pv.w; a_ds += d * d;
        }
    }

    // ---------- wave reduce (64 lanes) ----------
#pragma unroll
    for (int off = 32; off > 0; off >>= 1) {
        a_co += __shfl_down(a_co, off);
        a_ds += __shfl_down(a_ds, off);
        a_dr += __shfl_down(a_dr, off);
        a_dc += __shfl_down(a_dc, off);
    }

    __shared__ float s_co[4], s_ds[4], s_dr[4], s_dc[4];
    int wid  = threadIdx.x >> 6;
    int lane = threadIdx.x & 63;
    if (lane == 0) {
        s_co[wid] = a_co; s_ds[wid] = a_ds;
        s_dr[wid] = a_dr; s_dc[wid] = a_dc;
    }
    __syncthreads();
    if (threadIdx.x == 0) {
        float t_co = 0.f, t_s = 0.f, t_r = 0.f, t_c = 0.f;
        for (int w = 0; w < 4; ++w) {
            t_co += s_co[w]; t_s += s_ds[w];
            t_r += s_dr[w]; t_c += s_dc[w];
        }
        part[blockIdx.x] = make_float4(t_co, t_s, t_r, t_c);
    }
}

// Single block: reduce nblk float4 partials in double, emit the scalar.
__global__ __launch_bounds__(256) void scol_final(const float4* __restrict__ part,
                                                  float* __restrict__ out,
                                                  int nblk, int B) {
    double d_co = 0., d_ds = 0., d_dr = 0., d_dc = 0.;
    for (int i = threadIdx.x; i < nblk; i += blockDim.x) {
        float4 p = part[i];
        d_co += (double)p.x; d_ds += (double)p.y;
        d_dr += (double)p.z; d_dc += (double)p.w;
    }
#pragma unroll
    for (int off = 32; off > 0; off >>= 1) {
        d_co += __shfl_down(d_co, off);
        d_ds += __shfl_down(d_ds, off);
        d_dr += __shfl_down(d_dr, off);
        d_dc += __shfl_down(d_dc, off);
    }
    __shared__ double sh[4][4];
    int wid  = threadIdx.x >> 6;
    int lane = threadIdx.x & 63;
    if (lane == 0) {
        sh[wid][0] = d_co; sh[wid][1] = d_ds;
        sh[wid][2] = d_dr; sh[wid][3] = d_dc;
    }
    __syncthreads();
    if (threadIdx.x == 0) {
        double t_co = 0., t_ds = 0., t_dr = 0., t_dc = 0.;
        for (int w = 0; w < 4; ++w) {
            t_co += sh[w][0]; t_ds += sh[w][1];
            t_dr += sh[w][2]; t_dc += sh[w][3];
        }
        double nvox = (double)B * SS * RR * CC;
        double nds  = (double)B * (SS - 1) * RR * CC;
        double ndr  = (double)B * SS * (RR - 1) * CC;
        double ndc  = (double)B * SS * RR * (CC - 1);
        out[0] = (float)(0.5 * (t_co / nvox + t_ds / nds + t_dr / ndr + t_dc / ndc));
    }
}

extern "C" void kernel_launch(void* const* d_in, const int* in_sizes, int n_in,
                              void* d_out, int out_size, void* d_ws, size_t ws_size,
                              hipStream_t stream) {
    const float* L = (const float*)d_in[0];
    const float* U = (const float*)d_in[1];
    float* out = (float*)d_out;

    int B = in_sizes[1] / (9 * SS * RR * CC);
    int blocks = B * (SS / SCH) * (RR / 8);   // 1024 for B=2, co-resident grid

    float4* part = (float4*)d_ws;

    hipLaunchKernelGGL(scol_main, dim3(blocks), dim3(256), 0, stream,
                       L, U, part);
    hipLaunchKernelGGL(scol_final, dim3(1), dim3(256), 0, stream,
                       part, out, blocks, B);
}